// Round 12
// baseline (43.574 us; speedup 1.0000x reference)
//
#include <hip/hip_runtime.h>

#define W 512
#define NPIX 4194304              // 16 images * 512*512, per input

union Bytes { uint4 v; unsigned char b[16]; };
union B8 { uint2 v; unsigned char b[8]; };

__device__ __forceinline__ unsigned char gray1(float a, float b, float c) {
    // JAX f32 op order: ((c0+c1+c2)/3)*255, round-nearest-even
    return (unsigned char)__float2int_rn(((a + b + c) / 3.0f) * 255.0f);
}

// ---------------------------------------------------------------------------
// K1: pure gray map — no LDS, no minmax, no tiles. 8 px/thread.
// grid (2048, 2) = 4096 blocks = 8 blocks/CU resident -> 32 waves/CU.
// Per thread: 6 independent float4 loads (3 channels x 2) -> 8 grays -> 8B store.
// This is the whole 100.7 MB input stream at maximal latency hiding; the
// fused-tile k1 of R5-R11 was structurally capped at 16 waves/CU (R8: 39 us,
// 34% occ, latency-bound on L3 hits).
// ---------------------------------------------------------------------------
__global__ __launch_bounds__(256, 8) void k1_gray(
    const float4* __restrict__ og, const float4* __restrict__ gg,
    uint2* __restrict__ gray2) {
    int inp = blockIdx.y;
    int t = blockIdx.x * 256 + threadIdx.x;   // 0..524287 (8-px units per input)
    const float4* src = inp ? gg : og;
    int img = t >> 15;                        // 32768 units per image
    int u = t & 32767;
    size_t b = (size_t)img * 196608 + ((size_t)u << 1);

    float4 a0 = src[b],          a1 = src[b + 1];
    float4 b0 = src[b + 65536],  b1 = src[b + 65537];
    float4 c0 = src[b + 131072], c1 = src[b + 131073];

    B8 r;
    r.b[0] = gray1(a0.x, b0.x, c0.x);
    r.b[1] = gray1(a0.y, b0.y, c0.y);
    r.b[2] = gray1(a0.z, b0.z, c0.z);
    r.b[3] = gray1(a0.w, b0.w, c0.w);
    r.b[4] = gray1(a1.x, b1.x, c1.x);
    r.b[5] = gray1(a1.y, b1.y, c1.y);
    r.b[6] = gray1(a1.z, b1.z, c1.z);
    r.b[7] = gray1(a1.w, b1.w, c1.w);
    gray2[(size_t)inp * 524288 + t] = r.v;
}

// ---------------------------------------------------------------------------
// K2: minmax only, direct loads from L2/L3-hot gray. grid (1024, 2) = 8/CU.
// Thread = one 16-px row segment; rows r-1, r, r+1 as uint4 + 3 boundary bytes.
// joint = center*256 + shifted; SHIFTS=(1,0),(1,1),(0,1),(-1,1);
// shifted[r,c]=g[(r-dx)&511,(c-dy)&511].
// 8 u32 per block to distinct slots (no atomics).
// ---------------------------------------------------------------------------
__global__ __launch_bounds__(256, 8) void k2_minmax(
    const unsigned char* __restrict__ gray,
    unsigned int* __restrict__ blockmm) {
    int inp = blockIdx.y;
    const unsigned char* g = gray + (size_t)inp * NPIX;
    int t = blockIdx.x * 256 + threadIdx.x;   // segment id, 262144 per input
    int img = t >> 14;
    int p = t & 16383;
    int r = p >> 5;
    int c0 = (p & 31) << 4;
    const unsigned char* gn = g + (img << 18);
    int rm1 = (r - 1) & 511, rp1 = (r + 1) & 511, cp = (c0 - 1) & 511;

    Bytes rm, rc, rp;
    rm.v = *(const uint4*)(gn + (rm1 << 9) + c0);
    rc.v = *(const uint4*)(gn + (r   << 9) + c0);
    rp.v = *(const uint4*)(gn + (rp1 << 9) + c0);
    unsigned char pm = gn[(rm1 << 9) | cp];
    unsigned char pc = gn[(r   << 9) | cp];
    unsigned char pp = gn[(rp1 << 9) | cp];

    unsigned int lmin[4] = {~0u, ~0u, ~0u, ~0u};
    unsigned int lmax[4] = {0u, 0u, 0u, 0u};
#pragma unroll
    for (int j = 0; j < 16; ++j) {
        unsigned int base = ((unsigned int)rc.b[j]) << 8;
        unsigned int v0 = base + rm.b[j];
        unsigned int v1 = base + (j ? rm.b[j - 1] : pm);
        unsigned int v2 = base + (j ? rc.b[j - 1] : pc);
        unsigned int v3 = base + (j ? rp.b[j - 1] : pp);
        lmin[0] = min(lmin[0], v0); lmax[0] = max(lmax[0], v0);
        lmin[1] = min(lmin[1], v1); lmax[1] = max(lmax[1], v1);
        lmin[2] = min(lmin[2], v2); lmax[2] = max(lmax[2], v2);
        lmin[3] = min(lmin[3], v3); lmax[3] = max(lmax[3], v3);
    }
#pragma unroll
    for (int off = 32; off > 0; off >>= 1) {
#pragma unroll
        for (int s = 0; s < 4; ++s) {
            lmin[s] = min(lmin[s], (unsigned int)__shfl_down((int)lmin[s], off));
            lmax[s] = max(lmax[s], (unsigned int)__shfl_down((int)lmax[s], off));
        }
    }
    __shared__ unsigned int wmin[4][4], wmax[4][4];
    int wave = threadIdx.x >> 6;
    if ((threadIdx.x & 63) == 0) {
#pragma unroll
        for (int s = 0; s < 4; ++s) { wmin[wave][s] = lmin[s]; wmax[wave][s] = lmax[s]; }
    }
    __syncthreads();
    if (threadIdx.x < 4) {
        int s = threadIdx.x;
        unsigned int mn = min(min(wmin[0][s], wmin[1][s]), min(wmin[2][s], wmin[3][s]));
        unsigned int mx = max(max(wmax[0][s], wmax[1][s]), max(wmax[2][s], wmax[3][s]));
        blockmm[inp * 8192 + s * 1024 + blockIdx.x] = mn;
        blockmm[inp * 8192 + (4 + s) * 1024 + blockIdx.x] = mx;
    }
}

// ---------------------------------------------------------------------------
// K3: contrast, direct loads (R11 k2 pattern). grid (1024, 2) = 8/CU.
// Loads issued first to overlap the 1024x8 minmax-table reduce (L2-resident).
// per-pixel: t = (float)(v - vmin); b = min((int)(t*scale), 65535)
// [t>=0 so trunc==floor]; d=(b>>8)-(b&255); sum d^2 in u32; 4 partials/block.
// ---------------------------------------------------------------------------
__global__ __launch_bounds__(256, 8) void k3_contrast(
    const unsigned char* __restrict__ gray,
    const unsigned int* __restrict__ blockmm,
    unsigned int* __restrict__ partial) {
    int inp = blockIdx.y;
    const unsigned char* g = gray + (size_t)inp * NPIX;
    int t = blockIdx.x * 256 + threadIdx.x;
    int img = t >> 14;
    int p = t & 16383;
    int r = p >> 5;
    int c0 = (p & 31) << 4;
    const unsigned char* gn = g + (img << 18);
    int rm1 = (r - 1) & 511, rp1 = (r + 1) & 511, cp = (c0 - 1) & 511;

    Bytes rm, rc, rp;
    rm.v = *(const uint4*)(gn + (rm1 << 9) + c0);
    rc.v = *(const uint4*)(gn + (r   << 9) + c0);
    rp.v = *(const uint4*)(gn + (rp1 << 9) + c0);
    unsigned char pm = gn[(rm1 << 9) | cp];
    unsigned char pc = gn[(r   << 9) | cp];
    unsigned char pp = gn[(rp1 << 9) | cp];

    __shared__ unsigned int mmfin[8];
    {
        int s8 = threadIdx.x >> 5, lane = threadIdx.x & 31;
        const unsigned int* mb = blockmm + inp * 8192 + s8 * 1024;
        unsigned int v = mb[lane];
#pragma unroll
        for (int k = 1; k < 32; ++k) {
            unsigned int u = mb[lane + k * 32];
            v = (s8 < 4) ? min(v, u) : max(v, u);
        }
#pragma unroll
        for (int off = 16; off > 0; off >>= 1) {
            unsigned int u = (unsigned int)__shfl_down((int)v, off, 32);
            v = (s8 < 4) ? min(v, u) : max(v, u);
        }
        if (lane == 0) mmfin[s8] = v;
    }
    __syncthreads();

    unsigned int vm[4]; float scale[4];
#pragma unroll
    for (int s = 0; s < 4; ++s) {
        vm[s] = mmfin[s];
        scale[s] = 65536.0f / fmaxf((float)(mmfin[4 + s] - vm[s]), 1.0f);
    }

    unsigned int acc[4] = {0u, 0u, 0u, 0u};
#pragma unroll
    for (int j = 0; j < 16; ++j) {
        unsigned int base = ((unsigned int)rc.b[j]) << 8;
        unsigned int v[4];
        v[0] = base + rm.b[j];
        v[1] = base + (j ? rm.b[j - 1] : pm);
        v[2] = base + (j ? rc.b[j - 1] : pc);
        v[3] = base + (j ? rp.b[j - 1] : pp);
#pragma unroll
        for (int s = 0; s < 4; ++s) {
            int b = (int)((float)(v[s] - vm[s]) * scale[s]);  // t>=0: trunc==floor
            b = b > 65535 ? 65535 : b;
            int d = (b >> 8) - (b & 255);
            acc[s] += (unsigned int)(d * d);
        }
    }
#pragma unroll
    for (int off = 32; off > 0; off >>= 1)
#pragma unroll
        for (int s = 0; s < 4; ++s)
            acc[s] += (unsigned int)__shfl_down((int)acc[s], off);

    __shared__ unsigned int wsum[4][4];
    int wave = threadIdx.x >> 6;
    if ((threadIdx.x & 63) == 0) {
#pragma unroll
        for (int s = 0; s < 4; ++s) wsum[wave][s] = acc[s];
    }
    __syncthreads();
    if (threadIdx.x < 4) {
        int s = threadIdx.x;
        unsigned int tot = wsum[0][s] + wsum[1][s] + wsum[2][s] + wsum[3][s];
        partial[(inp * 4 + s) * 1024 + blockIdx.x] = tot;
    }
}

// ---------------------------------------------------------------------------
// K4: one block. Reduce 8 combos x 1024 partials (double, exact < 2^53),
// loss = mean_a |2*S_og/2^25 - 2*S_gg/2^25|
// ---------------------------------------------------------------------------
__global__ __launch_bounds__(256) void k4_loss(
    const unsigned int* __restrict__ partial, float* __restrict__ out) {
    int c = threadIdx.x >> 5;       // combo = inp*4 + s
    int lane = threadIdx.x & 31;
    const unsigned int* p = partial + c * 1024;
    double acc = 0.0;
#pragma unroll
    for (int k = 0; k < 32; ++k) acc += (double)p[lane + k * 32];
#pragma unroll
    for (int off = 16; off > 0; off >>= 1) acc += __shfl_down(acc, off, 32);
    __shared__ double cs[8];
    if (lane == 0) cs[c] = acc;
    __syncthreads();
    if (threadIdx.x == 0) {
        double r = 0.0;
        for (int a = 0; a < 4; ++a) {
            double co = 2.0 * cs[a]     / 33554432.0;
            double cg = 2.0 * cs[4 + a] / 33554432.0;
            r += fabs(co - cg);
        }
        out[0] = (float)(r * 0.25);
    }
}

extern "C" void kernel_launch(void* const* d_in, const int* in_sizes, int n_in,
                              void* d_out, int out_size, void* d_ws, size_t ws_size,
                              hipStream_t stream) {
    const float4* og = (const float4*)d_in[0];
    const float4* gg = (const float4*)d_in[1];
    float* out = (float*)d_out;

    // ws: blockmm u32[16384] @0 (64KB) | partial u32[8192] @64KB (32KB)
    //     | gray @128KB (8MB)
    unsigned int* blockmm = (unsigned int*)d_ws;
    unsigned int* partial = blockmm + 16384;
    unsigned char* gray = (unsigned char*)d_ws + 131072;

    dim3 g1(2048, 2);
    k1_gray<<<g1, 256, 0, stream>>>(og, gg, (uint2*)gray);
    dim3 g2(1024, 2);
    k2_minmax<<<g2, 256, 0, stream>>>(gray, blockmm);
    k3_contrast<<<g2, 256, 0, stream>>>(gray, blockmm, partial);
    k4_loss<<<1, 256, 0, stream>>>(partial, out);
}

// Round 13
// 39.530 us; speedup vs baseline: 1.1023x; 1.1023x over previous
//
#include <hip/hip_runtime.h>

#define W 512
#define NPIX 4194304              // 16 images * 512*512, per input

union Bytes { uint4 v; unsigned char b[16]; };

typedef float __attribute__((ext_vector_type(4))) f4v;

__device__ __forceinline__ f4v ntload(const float4* p) {
    // non-temporal read: bypass L2 allocation (input is read once per pass;
    // keeps the per-XCD 4MB L2 free for the gray store stream)
    return __builtin_nontemporal_load((const f4v*)p);
}

__device__ __forceinline__ unsigned char gray1(float a, float b, float c) {
    // JAX f32 op order: ((c0+c1+c2)/3)*255, round-nearest-even
    return (unsigned char)__float2int_rn(((a + b + c) / 3.0f) * 255.0f);
}

// ---------------------------------------------------------------------------
// K1: per block = one 16-row tile of one image of one input (grid 512 x 2).
// launch_bounds(256,4) -> VGPR cap 128; staging software-pipelined depth 1.
// Input reads are NON-TEMPORAL (only change vs R10 — A/B for L2 thrash).
//   - gray rows r0-1..r0+16 (18 rows incl. recomputed halo) -> LDS
//   - store main 16 rows to global gray buffer
//   - per-block min/max of joint = center*256 + shifted, 4 shifts
//     SHIFTS=(1,0),(1,1),(0,1),(-1,1); shifted[r,c]=g[(r-dx)&511,(c-dy)&511]
//   - 8 u32 per block to distinct global slots (no atomics)
// ---------------------------------------------------------------------------
__global__ __launch_bounds__(256, 4) void k1_gray_minmax(
    const float4* __restrict__ og, const float4* __restrict__ gg,
    uchar4* __restrict__ gray, unsigned int* __restrict__ blockmm) {
    int inp = blockIdx.y;
    int img = blockIdx.x >> 5;
    int r0 = (blockIdx.x & 31) << 4;
    const float4* src = (inp ? gg : og) + (size_t)img * 3 * 65536;
    uchar4* gout = gray + (size_t)inp * (NPIX / 4) + img * 65536;
    const float4* s0 = src;
    const float4* s1 = src + 65536;
    const float4* s2 = src + 131072;

    __shared__ unsigned char lds[18 * W];
    uchar4* lds4 = (uchar4*)lds;

    int off[9];
#pragma unroll
    for (int j = 0; j < 9; ++j) {
        int q = threadIdx.x + j * 256;
        int i = q >> 7, quad = q & 127;
        int ir = (r0 - 1 + i) & 511;
        off[j] = ir * 128 + quad;
    }
    f4v a = ntload(s0 + off[0]), b = ntload(s1 + off[0]), c = ntload(s2 + off[0]);
#pragma unroll
    for (int j = 0; j < 9; ++j) {
        f4v an, bn, cn;
        if (j < 8) {
            an = ntload(s0 + off[j + 1]);
            bn = ntload(s1 + off[j + 1]);
            cn = ntload(s2 + off[j + 1]);
        }
        uchar4 r;
        r.x = gray1(a.x, b.x, c.x);
        r.y = gray1(a.y, b.y, c.y);
        r.z = gray1(a.z, b.z, c.z);
        r.w = gray1(a.w, b.w, c.w);
        lds4[threadIdx.x + j * 256] = r;
        int i = (threadIdx.x + j * 256) >> 7;
        if (i >= 1 && i <= 16) gout[off[j]] = r;   // main rows only
        a = an; b = bn; c = cn;
    }
    __syncthreads();

    int lr = 1 + (threadIdx.x >> 4);
    int c0 = (threadIdx.x & 15) << 5;
    const unsigned char* Lm = lds + (lr - 1) * W;
    const unsigned char* Lc = lds + lr * W;
    const unsigned char* Lp = lds + (lr + 1) * W;
    Bytes rm[2], rc[2], rp[2];
    rm[0].v = *(const uint4*)(Lm + c0); rm[1].v = *(const uint4*)(Lm + c0 + 16);
    rc[0].v = *(const uint4*)(Lc + c0); rc[1].v = *(const uint4*)(Lc + c0 + 16);
    rp[0].v = *(const uint4*)(Lp + c0); rp[1].v = *(const uint4*)(Lp + c0 + 16);
    int cp = (c0 - 1) & 511;
    unsigned char pm = Lm[cp], pc = Lc[cp], pp = Lp[cp];

    unsigned int lmin[4] = {~0u, ~0u, ~0u, ~0u};
    unsigned int lmax[4] = {0u, 0u, 0u, 0u};
#pragma unroll
    for (int h = 0; h < 2; ++h) {
#pragma unroll
        for (int j = 0; j < 16; ++j) {
            unsigned int base = ((unsigned int)rc[h].b[j]) << 8;
            unsigned int v0 = base + rm[h].b[j];
            unsigned int v1 = base + (j ? rm[h].b[j - 1] : (h ? rm[0].b[15] : pm));
            unsigned int v2 = base + (j ? rc[h].b[j - 1] : (h ? rc[0].b[15] : pc));
            unsigned int v3 = base + (j ? rp[h].b[j - 1] : (h ? rp[0].b[15] : pp));
            lmin[0] = min(lmin[0], v0); lmax[0] = max(lmax[0], v0);
            lmin[1] = min(lmin[1], v1); lmax[1] = max(lmax[1], v1);
            lmin[2] = min(lmin[2], v2); lmax[2] = max(lmax[2], v2);
            lmin[3] = min(lmin[3], v3); lmax[3] = max(lmax[3], v3);
        }
    }
#pragma unroll
    for (int off2 = 32; off2 > 0; off2 >>= 1) {
#pragma unroll
        for (int s = 0; s < 4; ++s) {
            lmin[s] = min(lmin[s], (unsigned int)__shfl_down((int)lmin[s], off2));
            lmax[s] = max(lmax[s], (unsigned int)__shfl_down((int)lmax[s], off2));
        }
    }
    __shared__ unsigned int wmin[4][4], wmax[4][4];
    int wave = threadIdx.x >> 6;
    if ((threadIdx.x & 63) == 0) {
#pragma unroll
        for (int s = 0; s < 4; ++s) { wmin[wave][s] = lmin[s]; wmax[wave][s] = lmax[s]; }
    }
    __syncthreads();
    if (threadIdx.x < 4) {
        int s = threadIdx.x;
        unsigned int mn = min(min(wmin[0][s], wmin[1][s]), min(wmin[2][s], wmin[3][s]));
        unsigned int mx = max(max(wmax[0][s], wmax[1][s]), max(wmax[2][s], wmax[3][s]));
        blockmm[inp * 4096 + s * 512 + blockIdx.x] = mn;
        blockmm[inp * 4096 + (4 + s) * 512 + blockIdx.x] = mx;
    }
}

// ---------------------------------------------------------------------------
// K2: per block = same tile mapping (grid 512 x 2). (R10-proven, unchanged.)
//   - redundantly reduce this input's 512x8 block-minmax table (L2-resident)
//   - load gray tile+halo (18 rows) from global -> LDS, pipelined
//   - per-pixel: t = (float)(v - vmin); b = min((int)(t*scale), 65535)
//     [t >= 0 always, so (int) truncation == floor and no lower clamp]
//     d = (b>>8)-(b&255); accumulate d^2 in u32
//   - write 4 per-block partial sums to distinct slots (no atomics)
// ---------------------------------------------------------------------------
__global__ __launch_bounds__(256, 4) void k2_contrast(
    const uchar4* __restrict__ gray, const unsigned int* __restrict__ blockmm,
    unsigned int* __restrict__ partial) {
    int inp = blockIdx.y;
    int img = blockIdx.x >> 5;
    int r0 = (blockIdx.x & 31) << 4;

    __shared__ unsigned char lds[18 * W];
    __shared__ unsigned int mmfin[8];
    uchar4* lds4 = (uchar4*)lds;
    const uchar4* gin = gray + (size_t)inp * (NPIX / 4) + img * 65536;

    int off[9];
#pragma unroll
    for (int j = 0; j < 9; ++j) {
        int q = threadIdx.x + j * 256;
        int i = q >> 7, quad = q & 127;
        int ir = (r0 - 1 + i) & 511;
        off[j] = ir * 128 + quad;
    }
    uchar4 g0 = gin[off[0]];
#pragma unroll
    for (int j = 0; j < 9; ++j) {
        uchar4 gn;
        if (j < 8) gn = gin[off[j + 1]];
        lds4[threadIdx.x + j * 256] = g0;
        g0 = gn;
    }
    {
        int s8 = threadIdx.x >> 5, lane = threadIdx.x & 31;
        const unsigned int* mb = blockmm + inp * 4096 + s8 * 512;
        unsigned int v = mb[lane];
#pragma unroll
        for (int k = 1; k < 16; ++k) {
            unsigned int u = mb[lane + k * 32];
            v = (s8 < 4) ? min(v, u) : max(v, u);
        }
#pragma unroll
        for (int off2 = 16; off2 > 0; off2 >>= 1) {
            unsigned int u = (unsigned int)__shfl_down((int)v, off2, 32);
            v = (s8 < 4) ? min(v, u) : max(v, u);
        }
        if (lane == 0) mmfin[s8] = v;
    }
    __syncthreads();

    unsigned int vm[4]; float scale[4];
#pragma unroll
    for (int s = 0; s < 4; ++s) {
        vm[s] = mmfin[s];
        scale[s] = 65536.0f / fmaxf((float)(mmfin[4 + s] - vm[s]), 1.0f);
    }

    int lr = 1 + (threadIdx.x >> 4);
    int c0 = (threadIdx.x & 15) << 5;
    const unsigned char* Lm = lds + (lr - 1) * W;
    const unsigned char* Lc = lds + lr * W;
    const unsigned char* Lp = lds + (lr + 1) * W;
    Bytes rm[2], rc[2], rp[2];
    rm[0].v = *(const uint4*)(Lm + c0); rm[1].v = *(const uint4*)(Lm + c0 + 16);
    rc[0].v = *(const uint4*)(Lc + c0); rc[1].v = *(const uint4*)(Lc + c0 + 16);
    rp[0].v = *(const uint4*)(Lp + c0); rp[1].v = *(const uint4*)(Lp + c0 + 16);
    int cp = (c0 - 1) & 511;
    unsigned char pm = Lm[cp], pc = Lc[cp], pp = Lp[cp];

    unsigned int acc[4] = {0u, 0u, 0u, 0u};
#pragma unroll
    for (int h = 0; h < 2; ++h) {
#pragma unroll
        for (int j = 0; j < 16; ++j) {
            unsigned int base = ((unsigned int)rc[h].b[j]) << 8;
            unsigned int v[4];
            v[0] = base + rm[h].b[j];
            v[1] = base + (j ? rm[h].b[j - 1] : (h ? rm[0].b[15] : pm));
            v[2] = base + (j ? rc[h].b[j - 1] : (h ? rc[0].b[15] : pc));
            v[3] = base + (j ? rp[h].b[j - 1] : (h ? rp[0].b[15] : pp));
#pragma unroll
            for (int s = 0; s < 4; ++s) {
                int b = (int)((float)(v[s] - vm[s]) * scale[s]);  // t>=0: trunc==floor
                b = b > 65535 ? 65535 : b;
                int d = (b >> 8) - (b & 255);
                acc[s] += (unsigned int)(d * d);
            }
        }
    }
#pragma unroll
    for (int off2 = 32; off2 > 0; off2 >>= 1)
#pragma unroll
        for (int s = 0; s < 4; ++s)
            acc[s] += (unsigned int)__shfl_down((int)acc[s], off2);

    __shared__ unsigned int wsum[4][4];
    int wave = threadIdx.x >> 6;
    if ((threadIdx.x & 63) == 0) {
#pragma unroll
        for (int s = 0; s < 4; ++s) wsum[wave][s] = acc[s];
    }
    __syncthreads();
    if (threadIdx.x < 4) {
        int s = threadIdx.x;
        unsigned int tot = wsum[0][s] + wsum[1][s] + wsum[2][s] + wsum[3][s];
        partial[(inp * 4 + s) * 512 + blockIdx.x] = tot;
    }
}

// ---------------------------------------------------------------------------
// K3: one block. Reduce 8 combos x 512 partials (double, exact < 2^53),
// loss = mean_a |2*S_og/2^25 - 2*S_gg/2^25|
// ---------------------------------------------------------------------------
__global__ __launch_bounds__(256) void k3_loss(
    const unsigned int* __restrict__ partial, float* __restrict__ out) {
    int c = threadIdx.x >> 5;       // combo = inp*4 + s
    int lane = threadIdx.x & 31;
    const unsigned int* p = partial + c * 512;
    double acc = 0.0;
#pragma unroll
    for (int k = 0; k < 16; ++k) acc += (double)p[lane + k * 32];
#pragma unroll
    for (int off = 16; off > 0; off >>= 1) acc += __shfl_down(acc, off, 32);
    __shared__ double cs[8];
    if (lane == 0) cs[c] = acc;
    __syncthreads();
    if (threadIdx.x == 0) {
        double r = 0.0;
        for (int a = 0; a < 4; ++a) {
            double co = 2.0 * cs[a]     / 33554432.0;
            double cg = 2.0 * cs[4 + a] / 33554432.0;
            r += fabs(co - cg);
        }
        out[0] = (float)(r * 0.25);
    }
}

extern "C" void kernel_launch(void* const* d_in, const int* in_sizes, int n_in,
                              void* d_out, int out_size, void* d_ws, size_t ws_size,
                              hipStream_t stream) {
    const float4* og = (const float4*)d_in[0];
    const float4* gg = (const float4*)d_in[1];
    float* out = (float*)d_out;

    // ws: blockmm u32[8192] @0 (32KB) | partial u32[4096] @32KB (16KB)
    //     | gray @64KB (8MB)
    unsigned int* blockmm = (unsigned int*)d_ws;
    unsigned int* partial = blockmm + 8192;
    uchar4* gray = (uchar4*)((char*)d_ws + 65536);

    dim3 grid(512, 2);
    k1_gray_minmax<<<grid, 256, 0, stream>>>(og, gg, gray, blockmm);
    k2_contrast<<<grid, 256, 0, stream>>>(gray, blockmm, partial);
    k3_loss<<<1, 256, 0, stream>>>(partial, out);
}